// Round 3
// baseline (51970.624 us; speedup 1.0000x reference)
//
#include <hip/hip_runtime.h>
#include <hip/hip_cooperative_groups.h>

namespace cg = cooperative_groups;

// ManyToOne GRU: N=256, L=512, I=512, H=1024.
// Round 2: single persistent cooperative kernel.
//  - B-hi weights (147 KiB per 16-col tile) live in LDS for ALL 512 steps
//    (per-step kernels can never keep weights in L2: kernel-boundary L2
//    invalidation). B-lo streamed from cache (read-only, never stale).
//  - WG = (c: 16-col tile, m: 64 rows); 4 waves = 4-way K-split; intra-WG
//    reduction via 15 KiB LDS scratch; one grid.sync() per step.
//  - h carried fp32; A split to bf16 hi/lo in-register (same 3-product
//    split-precision numerics as rounds 0/1).

typedef unsigned short u16;
typedef unsigned int   u32;
typedef __attribute__((ext_vector_type(4))) float f32x4;
typedef __attribute__((ext_vector_type(8))) short s16x8;

constexpr int NB   = 256;
constexpr int LSEQ = 512;
constexpr int ISZ  = 512;
constexpr int HSZ  = 1024;

constexpr int TILE_U16   = 48 * 3 * 512;   // 73728 u16 per 16-col tile
constexpr int LDSB_BYTES = 147456;         // B-hi panels in LDS
constexpr int SCR_BYTES  = 15360;          // 12 sets * 16 cols * 80B
constexpr int LDS_TOTAL  = LDSB_BYTES + SCR_BYTES;   // 162816 <= 163840

__device__ __forceinline__ u16 bf16_trunc(float f) {
    union { float f; unsigned u; } v; v.f = f;
    return (u16)(v.u >> 16);
}
__device__ __forceinline__ float bf16_up(u16 h) {
    union { float f; unsigned u; } v; v.u = ((unsigned)h) << 16;
    return v.f;
}

#define GLL16(g, l) __builtin_amdgcn_global_load_lds(                          \
    (const __attribute__((address_space(1))) u32*)(g),                         \
    (__attribute__((address_space(3))) u32*)(l), 16, 0, 0)

#define MFMA3(acc, a_h, a_l, b_h, b_l)                                       \
    acc = __builtin_amdgcn_mfma_f32_16x16x32_bf16(a_h, b_h, acc, 0, 0, 0);   \
    acc = __builtin_amdgcn_mfma_f32_16x16x32_bf16(a_h, b_l, acc, 0, 0, 0);   \
    acc = __builtin_amdgcn_mfma_f32_16x16x32_bf16(a_l, b_h, acc, 0, 0, 0);

// ---------------------------------------------------------------- prep ----
// Panel layout per tile c: [kbg:48][plane:3][kg:4][col:16][e:8] u16.
// plane 0: r, 1: z, 2: n (k<512 -> W_ih(n), k>=512 -> W_hh(n)).
__global__ __launch_bounds__(256) void prep_kernel(
    const float* __restrict__ W_ih, const float* __restrict__ W_hh,
    const float* __restrict__ b_ih, const float* __restrict__ b_hh,
    const float* __restrict__ W_out,
    u16* __restrict__ Bhi, u16* __restrict__ Blo,
    float* __restrict__ Wt, float4* __restrict__ bias4)
{
    int idx = blockIdx.x * 256 + threadIdx.x;
    if (idx < 64 * TILE_U16) {
        int c   = idx / TILE_U16;
        int r1  = idx % TILE_U16;
        int kbg = r1 / 1536;
        int r2  = r1 % 1536;
        int p   = r2 / 512;
        int r3  = r2 % 512;
        int kg  = r3 >> 7;
        int col = (r3 >> 3) & 15;
        int e   = r3 & 7;
        int k   = kbg * 32 + kg * 8 + e;
        int gcol = c * 16 + col;
        float w = (k < ISZ) ? W_ih[(p * HSZ + gcol) * ISZ + k]
                            : W_hh[(p * HSZ + gcol) * HSZ + (k - ISZ)];
        u16 hi = bf16_trunc(w);
        Bhi[idx] = hi;
        Blo[idx] = bf16_trunc(w - bf16_up(hi));
    }
    if (idx < HSZ * ISZ) {           // Wt[k][i] = W_out[i][k]
        int i = idx % ISZ, k = idx / ISZ;
        Wt[idx] = W_out[i * HSZ + k];
    }
    if (idx < HSZ) {
        bias4[idx] = make_float4(b_ih[idx] + b_hh[idx],
                                 b_ih[HSZ + idx] + b_hh[HSZ + idx],
                                 b_ih[2 * HSZ + idx],
                                 b_hh[2 * HSZ + idx]);
    }
}

// ---------------------------------------------------------------- init ----
__global__ __launch_bounds__(256) void init_kernel(
    const float* __restrict__ h_in, float* __restrict__ hf0)
{
    int idx = blockIdx.x * 256 + threadIdx.x;
    hf0[idx] = h_in[idx];
}

// ---------------------------------------------------------- persistent ----
__device__ __forceinline__ void split8(const float* p, s16x8& hi, s16x8& lo) {
    f32x4 a = *(const f32x4*)p;
    f32x4 b = *(const f32x4*)(p + 4);
    #pragma unroll
    for (int e = 0; e < 8; ++e) {
        float f = (e < 4) ? a[e] : b[e - 4];
        union { float f; unsigned u; } v; v.f = f;
        u16 h = (u16)(v.u >> 16);
        union { float f; unsigned u; } w; w.u = ((unsigned)h) << 16;
        union { float f; unsigned u; } r; r.f = f - w.f;
        hi[e] = (short)h;
        lo[e] = (short)(r.u >> 16);
    }
}

__global__ __launch_bounds__(256, 1) void gru_persistent(
    const float* __restrict__ x,
    const u16* __restrict__ Bhi, const u16* __restrict__ Blo,
    const float4* __restrict__ bias4,
    float* __restrict__ hf0, float* __restrict__ hf1)
{
    extern __shared__ char lds[];
    u16*   ldsB = (u16*)lds;
    float* scr  = (float*)(lds + LDSB_BYTES);
    cg::grid_group grid = cg::this_grid();

    const int tid  = threadIdx.x;
    const int lane = tid & 63, wv = tid >> 6;
    const int lr   = lane & 15, kg = lane >> 4;
    const int bid  = blockIdx.x;
    // XCD-aware: XCD = bid%8 -> fixed m; c spread across XCD pair.
    const int m = (bid & 7) >> 1;
    const int c = (bid >> 3) | ((bid & 1) << 5);

    // stage B-hi into LDS once
    {
        const char* src = (const char*)(Bhi + (size_t)c * TILE_U16);
        #pragma unroll
        for (int i = 0; i < 36; ++i) {
            int seg = i * 4 + wv;
            GLL16(src + seg * 1024 + lane * 16, lds + seg * 1024);
        }
    }
    __syncthreads();

    const u16* blo = Blo + (size_t)c * TILE_U16;
    const float4 b4 = bias4[c * 16 + lr];

    for (int t = 0; t < LSEQ; ++t) {
        const float* __restrict__ cur = (t & 1) ? hf1 : hf0;
        float* __restrict__       nxt = (t & 1) ? hf0 : hf1;

        f32x4 acc[4][4];   // sets: 0=r, 1=z, 2=in(x), 3=hn(h); x 4 row-tiles
        #pragma unroll
        for (int s = 0; s < 4; ++s)
            #pragma unroll
            for (int r = 0; r < 4; ++r) acc[s][r] = (f32x4){0.f, 0.f, 0.f, 0.f};

        const int kbase = wv * 384;
        #pragma unroll 2
        for (int kb = 0; kb < 12; ++kb) {
            const int kglob = kbase + kb * 32;
            const int kbg   = wv * 12 + kb;
            const u16* lp = ldsB + kbg * 1536 + kg * 128 + lr * 8;
            s16x8 bh0 = *(const s16x8*)lp;
            s16x8 bh1 = *(const s16x8*)(lp + 512);
            s16x8 bh2 = *(const s16x8*)(lp + 1024);
            const u16* gp = blo + kbg * 1536 + kg * 128 + lr * 8;
            s16x8 bl0 = *(const s16x8*)gp;
            s16x8 bl1 = *(const s16x8*)(gp + 512);
            s16x8 bl2 = *(const s16x8*)(gp + 1024);

            const bool isx = (kglob < ISZ);
            const float* abase;
            size_t rstr;
            if (isx) { abase = x + (size_t)t * ISZ + kglob + kg * 8; rstr = (size_t)LSEQ * ISZ; }
            else     { abase = cur + (kglob - ISZ) + kg * 8;         rstr = HSZ; }

            #pragma unroll
            for (int rt = 0; rt < 4; ++rt) {
                const int nrow = m * 64 + rt * 16 + lr;
                const float* ap = abase + (size_t)nrow * rstr;
                s16x8 ah, al;
                split8(ap, ah, al);
                MFMA3(acc[0][rt], ah, al, bh0, bl0)
                MFMA3(acc[1][rt], ah, al, bh1, bl1)
                if (isx) { MFMA3(acc[2][rt], ah, al, bh2, bl2) }
                else     { MFMA3(acc[3][rt], ah, al, bh2, bl2) }
            }
        }

        // intra-WG K-reduction + gate epilogue, 4 row-tile rounds
        #pragma unroll
        for (int rt = 0; rt < 4; ++rt) {
            if (wv) {
                #pragma unroll
                for (int s = 0; s < 4; ++s)
                    *(f32x4*)(scr + ((wv - 1) * 4 + s) * 320 + lr * 20 + kg * 4)
                        = acc[s][rt];
            }
            __syncthreads();
            if (wv == 0) {
                f32x4 sr = acc[0][rt], sz = acc[1][rt];
                f32x4 si = acc[2][rt], sh = acc[3][rt];
                #pragma unroll
                for (int w2 = 0; w2 < 3; ++w2) {
                    sr += *(const f32x4*)(scr + (w2 * 4 + 0) * 320 + lr * 20 + kg * 4);
                    sz += *(const f32x4*)(scr + (w2 * 4 + 1) * 320 + lr * 20 + kg * 4);
                    si += *(const f32x4*)(scr + (w2 * 4 + 2) * 320 + lr * 20 + kg * 4);
                    sh += *(const f32x4*)(scr + (w2 * 4 + 3) * 320 + lr * 20 + kg * 4);
                }
                const int j = c * 16 + lr;
                #pragma unroll
                for (int i = 0; i < 4; ++i) {
                    const int nrow = m * 64 + rt * 16 + kg * 4 + i;
                    float rr  = 1.f / (1.f + __expf(-(sr[i] + b4.x)));
                    float zz  = 1.f / (1.f + __expf(-(sz[i] + b4.y)));
                    float pre = (si[i] + b4.z) + rr * (sh[i] + b4.w);
                    float e2  = __expf(2.f * pre);
                    float ng  = 1.f - 2.f / (e2 + 1.f);
                    float ho  = cur[nrow * HSZ + j];
                    nxt[nrow * HSZ + j] = (1.f - zz) * ng + zz * ho;
                }
            }
            __syncthreads();
        }

        __threadfence();     // release: flush h writes past L2
        grid.sync();
        __threadfence();     // acquire: drop stale L2 lines before reads
    }
}

// ---------------------------------------------------------------- head ----
__global__ __launch_bounds__(256) void head_kernel(
    const float* __restrict__ hfin, const float* __restrict__ Wt,
    const float* __restrict__ b_out, float* __restrict__ out)
{
    __shared__ float hrow[HSZ];
    const int n = blockIdx.x;
    const int tid = threadIdx.x;
    for (int k = tid; k < HSZ; k += 256) {
        float v = hfin[n * HSZ + k];
        hrow[k] = v;
        out[NB * ISZ + n * HSZ + k] = v;   // h_final output
    }
    __syncthreads();
    for (int j = tid; j < ISZ; j += 256) {
        float acc = b_out[j];
        #pragma unroll 8
        for (int k = 0; k < HSZ; ++k)
            acc = fmaf(hrow[k], Wt[k * ISZ + j], acc);
        out[n * ISZ + j] = acc;
    }
}

// -------------------------------------------------------------- launch ----
extern "C" void kernel_launch(void* const* d_in, const int* in_sizes, int n_in,
                              void* d_out, int out_size, void* d_ws, size_t ws_size,
                              hipStream_t stream) {
    (void)in_sizes; (void)n_in; (void)out_size; (void)ws_size;
    const float* x     = (const float*)d_in[0];
    const float* h_in  = (const float*)d_in[1];
    const float* W_ih  = (const float*)d_in[2];
    const float* b_ih  = (const float*)d_in[3];
    const float* W_hh  = (const float*)d_in[4];
    const float* b_hh  = (const float*)d_in[5];
    const float* W_out = (const float*)d_in[6];
    const float* b_out = (const float*)d_in[7];
    float* out = (float*)d_out;

    char* ws = (char*)d_ws;
    size_t o = 0;
    u16*    Bhi   = (u16*)(ws + o);    o += (size_t)64 * TILE_U16 * 2;  // 9,437,184
    u16*    Blo   = (u16*)(ws + o);    o += (size_t)64 * TILE_U16 * 2;  // 9,437,184
    float*  Wt    = (float*)(ws + o);  o += (size_t)HSZ * ISZ * 4;      // 2,097,152
    float4* bias4 = (float4*)(ws + o); o += (size_t)HSZ * 16;           //    16,384
    float*  hf0   = (float*)(ws + o);  o += (size_t)NB * HSZ * 4;       // 1,048,576
    float*  hf1   = (float*)(ws + o);  o += (size_t)NB * HSZ * 4;       // 1,048,576
    // total ~23.1 MB

    prep_kernel<<<(64 * TILE_U16) / 256, 256, 0, stream>>>(
        W_ih, W_hh, b_ih, b_hh, W_out, Bhi, Blo, Wt, bias4);
    init_kernel<<<(NB * HSZ) / 256, 256, 0, stream>>>(h_in, hf0);

    {
        const float* xp = x;
        const u16* bhip = Bhi;
        const u16* blop = Blo;
        const float4* b4p = bias4;
        float* h0p = hf0;
        float* h1p = hf1;
        void* args[] = {(void*)&xp, (void*)&bhip, (void*)&blop,
                        (void*)&b4p, (void*)&h0p, (void*)&h1p};
        hipLaunchCooperativeKernel((void*)gru_persistent, dim3(256), dim3(256),
                                   args, LDS_TOTAL, stream);
    }

    // t=511 writes hf0 (t odd -> nxt = hf0)
    head_kernel<<<NB, 256, 0, stream>>>(hf0, Wt, b_out, out);
}

// Round 4
// 10194.435 us; speedup vs baseline: 5.0979x; 5.0979x over previous
//
#include <hip/hip_runtime.h>

// ManyToOne GRU: N=256, L=512, I=512, H=1024.
// Round 3: per-step kernel, 512-thread WGs (8 waves = 2/SIMD, vs round-1's 1/SIMD).
//  - WG = (c: 16 cols, m: 64 rows)  [optimal shape: bytes = 6144*(3C+R), C*R=1024]
//  - waves = (rt: 4 row-tiles) x (kh: 2 K-halves of 768); LDS K-reduction at end.
//  - B staged in 6 groups of 48 KB, kh-halves interleaved so both wave classes
//    progress together; double-buffered (96 KB) + 12 KB scratch = 108 KB LDS.
//  - Numerics identical to rounds 0-2: bf16 hi/lo split panels, 3-product MFMA.

typedef unsigned short u16;
typedef unsigned int   u32;
typedef __attribute__((ext_vector_type(4))) float f32x4;
typedef __attribute__((ext_vector_type(8))) short s16x8;

constexpr int NB   = 256;
constexpr int LSEQ = 512;
constexpr int ISZ  = 512;
constexpr int HSZ  = 1024;

constexpr int KB_TOT    = 48;              // 32-k blocks per col-tile (K=1536)
constexpr int KBBYTES   = 6144;            // 3 planes * (hi+lo) * 1KB panel
constexpr int TILEBYTES = KB_TOT * KBBYTES;        // 294912 per 16-col tile
constexpr int GROUPS    = 6;
constexpr int GBYTES    = 8 * KBBYTES;             // 49152 per group (8 kb)
constexpr int SCROFF    = 2 * GBYTES;              // 98304
constexpr int LDS_TOTAL = SCROFF + 12288;          // 110592

__device__ __forceinline__ u16 bf16_trunc(float f) {
    union { float f; unsigned u; } v; v.f = f;
    return (u16)(v.u >> 16);
}
__device__ __forceinline__ float bf16_up(u16 h) {
    union { float f; unsigned u; } v; v.u = ((unsigned)h) << 16;
    return v.f;
}

#define GLL16(g, l) __builtin_amdgcn_global_load_lds(                          \
    (const __attribute__((address_space(1))) u32*)(g),                         \
    (__attribute__((address_space(3))) u32*)(l), 16, 0, 0)

#define MFMA3(acc, a_h, a_l, b_h, b_l)                                       \
    acc = __builtin_amdgcn_mfma_f32_16x16x32_bf16(a_h, b_h, acc, 0, 0, 0);   \
    acc = __builtin_amdgcn_mfma_f32_16x16x32_bf16(a_h, b_l, acc, 0, 0, 0);   \
    acc = __builtin_amdgcn_mfma_f32_16x16x32_bf16(a_l, b_h, acc, 0, 0, 0);

// ---------------------------------------------------------------- prep ----
// Panel layout per tile c (u16 idx): kb*3072 + (p*2+hl)*512 + kg*128 + col*8 + e
// kb<16: x-part (W_ih), kb>=16: h-part (W_hh). p: 0=r, 1=z, 2=n.
__global__ __launch_bounds__(256) void prep_kernel(
    const float* __restrict__ W_ih, const float* __restrict__ W_hh,
    const float* __restrict__ b_ih, const float* __restrict__ b_hh,
    const float* __restrict__ W_out,
    u16* __restrict__ Bws, float* __restrict__ Wt, float4* __restrict__ bias4)
{
    int idx = blockIdx.x * 256 + threadIdx.x;
    if (idx < 64 * KB_TOT * 3072) {
        int c   = idx / (KB_TOT * 3072);
        int r1  = idx % (KB_TOT * 3072);
        int kb  = r1 / 3072;
        int r2  = r1 % 3072;
        int ph  = r2 / 512;
        int p   = ph >> 1, hl = ph & 1;
        int r3  = r2 % 512;
        int kg  = r3 / 128;
        int col = (r3 / 8) % 16;
        int e   = r3 % 8;
        int kloc = kg * 8 + e;
        int gcol = c * 16 + col;
        float w;
        if (kb < 16) w = W_ih[(p * HSZ + gcol) * ISZ + kb * 32 + kloc];
        else         w = W_hh[(p * HSZ + gcol) * HSZ + (kb - 16) * 32 + kloc];
        u16 hi = bf16_trunc(w);
        Bws[idx] = hl ? bf16_trunc(w - bf16_up(hi)) : hi;
    }
    if (idx < HSZ * ISZ) {           // Wt[k][i] = W_out[i][k]
        int i = idx % ISZ, k = idx / ISZ;
        Wt[idx] = W_out[i * HSZ + k];
    }
    if (idx < HSZ) {
        bias4[idx] = make_float4(b_ih[idx] + b_hh[idx],
                                 b_ih[HSZ + idx] + b_hh[HSZ + idx],
                                 b_ih[2 * HSZ + idx],
                                 b_hh[2 * HSZ + idx]);
    }
}

// ---------------------------------------------------------------- init ----
__global__ __launch_bounds__(256) void init_kernel(
    const float* __restrict__ x, const float* __restrict__ h_in,
    u16* __restrict__ xhi0, u16* __restrict__ xlo0,
    float* __restrict__ h0f, u16* __restrict__ h0hi, u16* __restrict__ h0lo)
{
    int idx = blockIdx.x * 256 + threadIdx.x;    // 131072 threads
    {
        int n = idx >> 9, k = idx & (ISZ - 1);
        float v = x[(long)n * (LSEQ * ISZ) + k];
        u16 hi = bf16_trunc(v);
        xhi0[idx] = hi;
        xlo0[idx] = bf16_trunc(v - bf16_up(hi));
    }
    #pragma unroll
    for (int q = 0; q < 2; ++q) {
        int e = idx * 2 + q;
        float v = h_in[e];
        u16 hi = bf16_trunc(v);
        h0f[e]  = v;
        h0hi[e] = hi;
        h0lo[e] = bf16_trunc(v - bf16_up(hi));
    }
}

// ---------------------------------------------------------------- step ----
__global__ __launch_bounds__(512, 1) void gru_step(
    const float* __restrict__ x, int t,
    const u16* __restrict__ Bws, const float4* __restrict__ bias4,
    const u16* __restrict__ xhi, const u16* __restrict__ xlo,
    u16* __restrict__ xhi_n, u16* __restrict__ xlo_n,
    const float* __restrict__ hf,
    const u16* __restrict__ hhi, const u16* __restrict__ hlo,
    float* __restrict__ hf_n,
    u16* __restrict__ hhi_n, u16* __restrict__ hlo_n)
{
    extern __shared__ char lds[];
    float* scr = (float*)(lds + SCROFF);

    const int tid  = threadIdx.x;
    const int lane = tid & 63;
    const int wv   = tid >> 6;               // 0..7
    const int rt   = wv & 3;                 // row-tile
    const int kh   = wv >> 2;                // K-half
    const int raw  = blockIdx.x;             // 0..255
    const int c    = ((raw & 7) << 3) | ((raw >> 3) & 7);  // same-c -> same XCD
    const int m    = raw >> 6;
    const int lr   = lane & 15;
    const int kg   = lane >> 4;
    const int fro  = kg * 256 + lr * 16;     // byte offset within 1KB panel

    const char* tsrc = (const char*)Bws + (size_t)c * TILEBYTES;

    // stage group 0: 48 segments of 1KB; seg<24 from kh0 chunk, else kh1 chunk
    #pragma unroll
    for (int i = 0; i < 6; ++i) {
        int seg = i * 8 + wv;
        const char* s = (seg < 24) ? tsrc + seg * 1024
                                   : tsrc + 147456 + (seg - 24) * 1024;
        GLL16(s + lane * 16, lds + seg * 1024);
    }

    // x_{t+1} conversion (1 elem/thread) — overlaps group-0 staging latency
    if (t + 1 < LSEQ) {
        int e = raw * 512 + tid;
        int n = e >> 9, k = e & (ISZ - 1);
        float v = x[(size_t)n * (LSEQ * ISZ) + (size_t)(t + 1) * ISZ + k];
        u16 hi = bf16_trunc(v);
        xhi_n[e] = hi;
        xlo_n[e] = bf16_trunc(v - bf16_up(hi));
    }

    const int nrow = m * 64 + rt * 16 + lr;
    const u16* pXh = xhi + nrow * ISZ + kg * 8;
    const u16* pXl = xlo + nrow * ISZ + kg * 8;
    const u16* pHh = hhi + nrow * HSZ + kg * 8;
    const u16* pHl = hlo + nrow * HSZ + kg * 8;

    f32x4 acc_r  = {0.f, 0.f, 0.f, 0.f};
    f32x4 acc_z  = acc_r, acc_in = acc_r, acc_hn = acc_r;

    #pragma unroll
    for (int g = 0; g < GROUPS; ++g) {
        __syncthreads();                     // buf[g&1] staged & visible
        if (g + 1 < GROUPS) {
            #pragma unroll
            for (int i = 0; i < 6; ++i) {
                int seg = i * 8 + wv;
                const char* s = (seg < 24)
                    ? tsrc + (g + 1) * 24576 + seg * 1024
                    : tsrc + 147456 + (g + 1) * 24576 + (seg - 24) * 1024;
                GLL16(s + lane * 16, lds + ((g + 1) & 1) * GBYTES + seg * 1024);
            }
        }
        const char* buf = lds + (g & 1) * GBYTES;
        #pragma unroll
        for (int j = 0; j < 4; ++j) {
            const char* pb = buf + (kh * 4 + j) * KBBYTES;
            s16x8 b0h = *(const s16x8*)(pb + fro);
            s16x8 b0l = *(const s16x8*)(pb + 1024 + fro);
            s16x8 b1h = *(const s16x8*)(pb + 2048 + fro);
            s16x8 b1l = *(const s16x8*)(pb + 3072 + fro);
            s16x8 b2h = *(const s16x8*)(pb + 4096 + fro);
            s16x8 b2l = *(const s16x8*)(pb + 5120 + fro);
            const int kbg = kh * 24 + g * 4 + j;   // global 32-k block
            const bool isx = (kbg < 16);
            s16x8 ah, al;
            if (isx) { ah = *(const s16x8*)(pXh + kbg * 32);
                       al = *(const s16x8*)(pXl + kbg * 32); }
            else     { ah = *(const s16x8*)(pHh + (kbg - 16) * 32);
                       al = *(const s16x8*)(pHl + (kbg - 16) * 32); }
            MFMA3(acc_r, ah, al, b0h, b0l)
            MFMA3(acc_z, ah, al, b1h, b1l)
            if (isx) { MFMA3(acc_in, ah, al, b2h, b2l) }
            else     { MFMA3(acc_hn, ah, al, b2h, b2l) }
        }
    }

    // cross-wave K reduction (kh=1 partials -> kh=0 waves)
    if (kh == 1) {
        *(f32x4*)(scr + ((rt * 3 + 0) * 64 + lane) * 4) = acc_r;
        *(f32x4*)(scr + ((rt * 3 + 1) * 64 + lane) * 4) = acc_z;
        *(f32x4*)(scr + ((rt * 3 + 2) * 64 + lane) * 4) = acc_hn;
    }
    __syncthreads();
    if (kh == 0) {
        acc_r  += *(const f32x4*)(scr + ((rt * 3 + 0) * 64 + lane) * 4);
        acc_z  += *(const f32x4*)(scr + ((rt * 3 + 1) * 64 + lane) * 4);
        acc_hn += *(const f32x4*)(scr + ((rt * 3 + 2) * 64 + lane) * 4);
        const int j  = c * 16 + lr;
        const float4 b4 = bias4[j];
        #pragma unroll
        for (int i = 0; i < 4; ++i) {
            const int row = m * 64 + rt * 16 + kg * 4 + i;
            float rr  = 1.f / (1.f + __expf(-(acc_r[i] + b4.x)));
            float zz  = 1.f / (1.f + __expf(-(acc_z[i] + b4.y)));
            float pre = (acc_in[i] + b4.z) + rr * (acc_hn[i] + b4.w);
            float e2  = __expf(2.f * pre);
            float ng  = 1.f - 2.f / (e2 + 1.f);
            float ho  = hf[row * HSZ + j];
            float hn  = (1.f - zz) * ng + zz * ho;
            hf_n[row * HSZ + j] = hn;
            u16 hi = bf16_trunc(hn);
            hhi_n[row * HSZ + j] = hi;
            hlo_n[row * HSZ + j] = bf16_trunc(hn - bf16_up(hi));
        }
    }
}

// ---------------------------------------------------------------- head ----
__global__ __launch_bounds__(256) void head_kernel(
    const float* __restrict__ hfin, const float* __restrict__ Wt,
    const float* __restrict__ b_out, float* __restrict__ out)
{
    __shared__ float hrow[HSZ];
    const int n = blockIdx.x;
    const int tid = threadIdx.x;
    for (int k = tid; k < HSZ; k += 256) {
        float v = hfin[n * HSZ + k];
        hrow[k] = v;
        out[NB * ISZ + n * HSZ + k] = v;   // h_final output
    }
    __syncthreads();
    for (int j = tid; j < ISZ; j += 256) {
        float acc = b_out[j];
        #pragma unroll 8
        for (int k = 0; k < HSZ; ++k)
            acc = fmaf(hrow[k], Wt[k * ISZ + j], acc);
        out[n * ISZ + j] = acc;
    }
}

// -------------------------------------------------------------- launch ----
extern "C" void kernel_launch(void* const* d_in, const int* in_sizes, int n_in,
                              void* d_out, int out_size, void* d_ws, size_t ws_size,
                              hipStream_t stream) {
    (void)in_sizes; (void)n_in; (void)out_size; (void)ws_size;
    const float* x     = (const float*)d_in[0];
    const float* h_in  = (const float*)d_in[1];
    const float* W_ih  = (const float*)d_in[2];
    const float* b_ih  = (const float*)d_in[3];
    const float* W_hh  = (const float*)d_in[4];
    const float* b_hh  = (const float*)d_in[5];
    const float* W_out = (const float*)d_in[6];
    const float* b_out = (const float*)d_in[7];
    float* out = (float*)d_out;

    char* ws = (char*)d_ws;
    size_t o = 0;
    u16*    Bws   = (u16*)(ws + o);    o += (size_t)64 * TILEBYTES;   // 18,874,368
    float*  Wt    = (float*)(ws + o);  o += (size_t)HSZ * ISZ * 4;    //  2,097,152
    float4* bias4 = (float4*)(ws + o); o += (size_t)HSZ * 16;         //     16,384
    float* hf[2]; u16 *hhi[2], *hlo[2], *xhi[2], *xlo[2];
    for (int b = 0; b < 2; ++b) { hf[b]  = (float*)(ws + o); o += (size_t)NB * HSZ * 4; }
    for (int b = 0; b < 2; ++b) { hhi[b] = (u16*)(ws + o);   o += (size_t)NB * HSZ * 2; }
    for (int b = 0; b < 2; ++b) { hlo[b] = (u16*)(ws + o);   o += (size_t)NB * HSZ * 2; }
    for (int b = 0; b < 2; ++b) { xhi[b] = (u16*)(ws + o);   o += (size_t)NB * ISZ * 2; }
    for (int b = 0; b < 2; ++b) { xlo[b] = (u16*)(ws + o);   o += (size_t)NB * ISZ * 2; }
    // total ~24.6 MB

    prep_kernel<<<(64 * KB_TOT * 3072) / 256, 256, 0, stream>>>(
        W_ih, W_hh, b_ih, b_hh, W_out, Bws, Wt, bias4);
    init_kernel<<<(NB * ISZ) / 256, 256, 0, stream>>>(
        x, h_in, xhi[0], xlo[0], hf[0], hhi[0], hlo[0]);

    for (int t = 0; t < LSEQ; ++t) {
        const int cur = t & 1, nxt = cur ^ 1;
        gru_step<<<256, 512, LDS_TOTAL, stream>>>(
            x, t, Bws, bias4,
            xhi[cur], xlo[cur], xhi[nxt], xlo[nxt],
            hf[cur], hhi[cur], hlo[cur],
            hf[nxt], hhi[nxt], hlo[nxt]);
    }
    head_kernel<<<NB, 256, 0, stream>>>(hf[0], Wt, b_out, out);
}

// Round 5
// 6747.189 us; speedup vs baseline: 7.7026x; 1.5109x over previous
//
#include <hip/hip_runtime.h>

// ManyToOne GRU: N=256, L=512, I=512, H=1024.
// Round 4: per-step kernel, 768 threads (12 waves = 3/SIMD).
//  - A (x, h) single-plane bf16 RTN: halves A traffic. h_old kept f32 for the
//    z*h blend (state not corrupted). B stays 2-limb hi/lo (accurate weights).
//  - B-hi (147,456 B) staged to LDS in ONE shot (1 barrier); B-lo read from L2
//    in-loop. Wave = 12-way K-split (4 kb each; waves 0-3 x-part, 4-11 h-part),
//    all 4 row-tiles computed per wave (B read ONCE per CU).
//  - 3-round LDS reduction tree (reuses staging buffer), 4-wave epilogue.
//  - 5 barriers/step total (vs round-3's 8); LDS reads 147 KB (vs 1.15 MB).

typedef unsigned short u16;
typedef unsigned int   u32;
typedef __attribute__((ext_vector_type(4))) float f32x4;
typedef __attribute__((ext_vector_type(8))) short s16x8;

constexpr int NB   = 256;
constexpr int LSEQ = 512;
constexpr int ISZ  = 512;
constexpr int HSZ  = 1024;

constexpr int TILE_U16  = 48 * 1536;       // 73728 u16 per 16-col tile (1 plane)
constexpr int TILEBYTES = TILE_U16 * 2;    // 147456
constexpr int LDS_TOTAL = TILEBYTES;       // staging; reduction reuses it

__device__ __forceinline__ u16 bf16_trunc(float f) {
    union { float f; unsigned u; } v; v.f = f;
    return (u16)(v.u >> 16);
}
__device__ __forceinline__ float bf16_up(u16 h) {
    union { float f; unsigned u; } v; v.u = ((unsigned)h) << 16;
    return v.f;
}
__device__ __forceinline__ u16 bf16_rtn(float f) {
    union { float f; unsigned u; } v; v.f = f;
    u32 u = v.u;
    u += 0x7FFFu + ((u >> 16) & 1u);       // round to nearest even
    return (u16)(u >> 16);
}

#define GLL16(g, l) __builtin_amdgcn_global_load_lds(                          \
    (const __attribute__((address_space(1))) u32*)(g),                         \
    (__attribute__((address_space(3))) u32*)(l), 16, 0, 0)

#define MFMA2(acc, a, b_h, b_l)                                              \
    acc = __builtin_amdgcn_mfma_f32_16x16x32_bf16(a, b_h, acc, 0, 0, 0);     \
    acc = __builtin_amdgcn_mfma_f32_16x16x32_bf16(a, b_l, acc, 0, 0, 0);

// ---------------------------------------------------------------- prep ----
// Panel layout per tile c (u16 idx within plane): kb*1536 + p*512 + kg*128 +
// col*8 + e.  kb<16: x-part (W_ih), kb>=16: h-part (W_hh). p: 0=r, 1=z, 2=n.
__global__ __launch_bounds__(256) void prep_kernel(
    const float* __restrict__ W_ih, const float* __restrict__ W_hh,
    const float* __restrict__ b_ih, const float* __restrict__ b_hh,
    const float* __restrict__ W_out,
    u16* __restrict__ Bhi, u16* __restrict__ Blo,
    float* __restrict__ Wt, float4* __restrict__ bias4)
{
    int idx = blockIdx.x * 256 + threadIdx.x;
    if (idx < 64 * TILE_U16) {
        int c   = idx / TILE_U16;
        int r1  = idx % TILE_U16;
        int kb  = r1 / 1536;
        int r2  = r1 % 1536;
        int p   = r2 / 512;
        int r3  = r2 % 512;
        int kg  = r3 >> 7;
        int col = (r3 >> 3) & 15;
        int e   = r3 & 7;
        int kloc = kg * 8 + e;
        int gcol = c * 16 + col;
        float w;
        if (kb < 16) w = W_ih[(p * HSZ + gcol) * ISZ + kb * 32 + kloc];
        else         w = W_hh[(p * HSZ + gcol) * HSZ + (kb - 16) * 32 + kloc];
        u16 hi = bf16_trunc(w);
        Bhi[idx] = hi;
        Blo[idx] = bf16_trunc(w - bf16_up(hi));
    }
    if (idx < HSZ * ISZ) {           // Wt[k][i] = W_out[i][k]
        int i = idx % ISZ, k = idx / ISZ;
        Wt[idx] = W_out[i * HSZ + k];
    }
    if (idx < HSZ) {
        bias4[idx] = make_float4(b_ih[idx] + b_hh[idx],
                                 b_ih[HSZ + idx] + b_hh[HSZ + idx],
                                 b_ih[2 * HSZ + idx],
                                 b_hh[2 * HSZ + idx]);
    }
}

// ---------------------------------------------------------------- init ----
__global__ __launch_bounds__(256) void init_kernel(
    const float* __restrict__ x, const float* __restrict__ h_in,
    u16* __restrict__ xb0, float* __restrict__ hf0, u16* __restrict__ hb0)
{
    int idx = blockIdx.x * 256 + threadIdx.x;    // 131072 threads
    {
        int n = idx >> 9, k = idx & (ISZ - 1);
        xb0[idx] = bf16_rtn(x[(size_t)n * (LSEQ * ISZ) + k]);
    }
    #pragma unroll
    for (int q = 0; q < 2; ++q) {
        int e = idx * 2 + q;
        float v = h_in[e];
        hf0[e] = v;
        hb0[e] = bf16_rtn(v);
    }
}

// ---------------------------------------------------------------- step ----
__global__ __launch_bounds__(768, 1) void gru_step(
    const float* __restrict__ x, int t,
    const u16* __restrict__ Bhi, const u16* __restrict__ Blo,
    const float4* __restrict__ bias4,
    const u16* __restrict__ xb, u16* __restrict__ xb_n,
    const float* __restrict__ hf, const u16* __restrict__ hb,
    float* __restrict__ hf_n, u16* __restrict__ hb_n)
{
    extern __shared__ char lds[];

    const int tid  = threadIdx.x;
    const int lane = tid & 63;
    const int wv   = tid >> 6;               // 0..11
    const int raw  = blockIdx.x;             // 0..255
    const int c    = ((raw & 7) << 3) | ((raw >> 3) & 7);  // tiles 8X..8X+7 on XCD X
    const int m    = raw >> 6;
    const int lr   = lane & 15;
    const int kg   = lane >> 4;
    const int fro  = kg * 256 + lr * 16;     // byte offset within 1KB panel

    const char* tsrc = (const char*)Bhi + (size_t)c * TILEBYTES;

    // ---- stage entire B-hi tile (147,456 B = 144 segs of 1 KB) ----
    #pragma unroll
    for (int i = 0; i < 12; ++i) {
        int seg = i * 12 + wv;
        GLL16(tsrc + seg * 1024 + lane * 16, lds + seg * 1024);
    }

    // ---- x_{t+1} conversion (512 elems per WG) — overlaps staging ----
    if (t + 1 < LSEQ && tid < 512) {
        int e = raw * 512 + tid;
        int n = e >> 9, k = e & (ISZ - 1);
        xb_n[e] = bf16_rtn(x[(size_t)n * (LSEQ * ISZ) + (size_t)(t + 1) * ISZ + k]);
    }

    __syncthreads();                         // (stage) B-hi visible

    // ---- main loop: wave wv owns kb = 4wv..4wv+3; computes all 4 row-tiles
    f32x4 acc[4][4];   // [rt][set]: 0=r, 1=z, 2=n_x, 3=n_h
    #pragma unroll
    for (int rt = 0; rt < 4; ++rt)
        #pragma unroll
        for (int s = 0; s < 4; ++s) acc[rt][s] = (f32x4){0.f, 0.f, 0.f, 0.f};

    const u16* blo = Blo + (size_t)c * TILE_U16;
    const bool isx = (wv < 4);

    #pragma unroll
    for (int j = 0; j < 4; ++j) {
        const int kbg = wv * 4 + j;
        const char* lp = lds + kbg * 3072 + fro;
        s16x8 bh0 = *(const s16x8*)lp;
        s16x8 bh1 = *(const s16x8*)(lp + 1024);
        s16x8 bh2 = *(const s16x8*)(lp + 2048);
        const u16* gp = blo + kbg * 1536 + kg * 128 + lr * 8;
        s16x8 bl0 = *(const s16x8*)gp;
        s16x8 bl1 = *(const s16x8*)(gp + 512);
        s16x8 bl2 = *(const s16x8*)(gp + 1024);

        #pragma unroll
        for (int rt = 0; rt < 4; ++rt) {
            const int row = m * 64 + rt * 16 + lr;
            s16x8 a;
            if (isx) a = *(const s16x8*)(xb + row * ISZ + kbg * 32 + kg * 8);
            else     a = *(const s16x8*)(hb + row * HSZ + (kbg - 16) * 32 + kg * 8);
            MFMA2(acc[rt][0], a, bh0, bl0)
            MFMA2(acc[rt][1], a, bh1, bl1)
            if (isx) { MFMA2(acc[rt][2], a, bh2, bl2) }
            else     { MFMA2(acc[rt][3], a, bh2, bl2) }
        }
    }

    // ---- 12-way reduction tree in LDS (reuses staging buffer) ----
    // slot s at floats [s*4096, (s+1)*4096): entry ((rt*4+set)*64+lane)*4
    float* scrf = (float*)lds;
    __syncthreads();                         // (a) done reading B-hi
    if (wv >= 6) {                           // R1 write: waves 6..11 -> slots 0..5
        float* sp = scrf + (wv - 6) * 4096 + lane * 4;
        #pragma unroll
        for (int rt = 0; rt < 4; ++rt)
            #pragma unroll
            for (int s = 0; s < 4; ++s)
                *(f32x4*)(sp + (rt * 4 + s) * 256) = acc[rt][s];
    }
    __syncthreads();                         // (b)
    if (wv < 6) {                            // R1 add
        const float* sp = scrf + wv * 4096 + lane * 4;
        #pragma unroll
        for (int rt = 0; rt < 4; ++rt)
            #pragma unroll
            for (int s = 0; s < 4; ++s)
                acc[rt][s] += *(const f32x4*)(sp + (rt * 4 + s) * 256);
    }
    if (wv >= 3 && wv < 6) {                 // R2 write: waves 3..5 -> slots 6..8
        float* sp = scrf + (wv + 3) * 4096 + lane * 4;
        #pragma unroll
        for (int rt = 0; rt < 4; ++rt)
            #pragma unroll
            for (int s = 0; s < 4; ++s)
                *(f32x4*)(sp + (rt * 4 + s) * 256) = acc[rt][s];
    }
    __syncthreads();                         // (c)
    if (wv < 3) {                            // R2 add; then R3 write slots 0..2
        const float* sp = scrf + (wv + 6) * 4096 + lane * 4;
        float* wp = scrf + wv * 4096 + lane * 4;
        #pragma unroll
        for (int rt = 0; rt < 4; ++rt)
            #pragma unroll
            for (int s = 0; s < 4; ++s) {
                acc[rt][s] += *(const f32x4*)(sp + (rt * 4 + s) * 256);
                *(f32x4*)(wp + (rt * 4 + s) * 256) = acc[rt][s];
            }
    }
    __syncthreads();                         // (d)

    // ---- epilogue: wave w in 0..3 owns rt = w ----
    if (wv < 4) {
        const int rt = wv;
        f32x4 sr = {0,0,0,0}, sz = sr, sx = sr, sh = sr;
        #pragma unroll
        for (int sl = 0; sl < 3; ++sl) {
            const float* sp = scrf + sl * 4096 + lane * 4;
            sr += *(const f32x4*)(sp + (rt * 4 + 0) * 256);
            sz += *(const f32x4*)(sp + (rt * 4 + 1) * 256);
            sx += *(const f32x4*)(sp + (rt * 4 + 2) * 256);
            sh += *(const f32x4*)(sp + (rt * 4 + 3) * 256);
        }
        const int j = c * 16 + lr;
        const float4 b4 = bias4[j];
        #pragma unroll
        for (int i = 0; i < 4; ++i) {
            const int row = m * 64 + rt * 16 + kg * 4 + i;
            float rr  = 1.f / (1.f + __expf(-(sr[i] + b4.x)));
            float zz  = 1.f / (1.f + __expf(-(sz[i] + b4.y)));
            float pre = (sx[i] + b4.z) + rr * (sh[i] + b4.w);
            float e2  = __expf(2.f * pre);
            float ng  = 1.f - 2.f / (e2 + 1.f);
            float ho  = hf[row * HSZ + j];
            float hn  = (1.f - zz) * ng + zz * ho;
            hf_n[row * HSZ + j] = hn;
            hb_n[row * HSZ + j] = bf16_rtn(hn);
        }
    }
}

// ---------------------------------------------------------------- head ----
__global__ __launch_bounds__(256) void head_kernel(
    const float* __restrict__ hfin, const float* __restrict__ Wt,
    const float* __restrict__ b_out, float* __restrict__ out)
{
    __shared__ float hrow[HSZ];
    const int n = blockIdx.x;
    const int tid = threadIdx.x;
    for (int k = tid; k < HSZ; k += 256) {
        float v = hfin[n * HSZ + k];
        hrow[k] = v;
        out[NB * ISZ + n * HSZ + k] = v;   // h_final output
    }
    __syncthreads();
    for (int j = tid; j < ISZ; j += 256) {
        float acc = b_out[j];
        #pragma unroll 8
        for (int k = 0; k < HSZ; ++k)
            acc = fmaf(hrow[k], Wt[k * ISZ + j], acc);
        out[n * ISZ + j] = acc;
    }
}

// -------------------------------------------------------------- launch ----
extern "C" void kernel_launch(void* const* d_in, const int* in_sizes, int n_in,
                              void* d_out, int out_size, void* d_ws, size_t ws_size,
                              hipStream_t stream) {
    (void)in_sizes; (void)n_in; (void)out_size; (void)ws_size;
    const float* x     = (const float*)d_in[0];
    const float* h_in  = (const float*)d_in[1];
    const float* W_ih  = (const float*)d_in[2];
    const float* b_ih  = (const float*)d_in[3];
    const float* W_hh  = (const float*)d_in[4];
    const float* b_hh  = (const float*)d_in[5];
    const float* W_out = (const float*)d_in[6];
    const float* b_out = (const float*)d_in[7];
    float* out = (float*)d_out;

    char* ws = (char*)d_ws;
    size_t o = 0;
    u16*    Bhi   = (u16*)(ws + o);    o += (size_t)64 * TILEBYTES;   // 9,437,184
    u16*    Blo   = (u16*)(ws + o);    o += (size_t)64 * TILEBYTES;   // 9,437,184
    float*  Wt    = (float*)(ws + o);  o += (size_t)HSZ * ISZ * 4;    // 2,097,152
    float4* bias4 = (float4*)(ws + o); o += (size_t)HSZ * 16;         //    16,384
    float* hf[2]; u16 *hb[2], *xb[2];
    for (int b = 0; b < 2; ++b) { hf[b] = (float*)(ws + o); o += (size_t)NB * HSZ * 4; }
    for (int b = 0; b < 2; ++b) { hb[b] = (u16*)(ws + o);   o += (size_t)NB * HSZ * 2; }
    for (int b = 0; b < 2; ++b) { xb[b] = (u16*)(ws + o);   o += (size_t)NB * ISZ * 2; }
    // total ~24.6 MB

    prep_kernel<<<(64 * TILE_U16) / 256, 256, 0, stream>>>(
        W_ih, W_hh, b_ih, b_hh, W_out, Bhi, Blo, Wt, bias4);
    init_kernel<<<(NB * ISZ) / 256, 256, 0, stream>>>(
        x, h_in, xb[0], hf[0], hb[0]);

    for (int t = 0; t < LSEQ; ++t) {
        const int cur = t & 1, nxt = cur ^ 1;
        gru_step<<<256, 768, LDS_TOTAL, stream>>>(
            x, t, Bhi, Blo, bias4,
            xb[cur], xb[nxt],
            hf[cur], hb[cur],
            hf[nxt], hb[nxt]);
    }
    head_kernel<<<NB, 256, 0, stream>>>(hf[0], Wt, b_out, out);
}